// Round 3
// baseline (131.731 us; speedup 1.0000x reference)
//
#include <hip/hip_runtime.h>

#define PCX 512.0f
#define PCY 512.0f

typedef float f32x4 __attribute__((ext_vector_type(4)));

// ---------------------------------------------------------------------------
// Setup: compose R = Rx(a) @ Ry(b) @ Rz(c) and pack [R(9), t(3)] per view.
//   row0 = [ cb*cc,            -cb*sc,            sb    ]
//   row1 = [ ca*sc + sa*sb*cc,  ca*cc - sa*sb*sc, -sa*cb]
//   row2 = [ sa*sc - ca*sb*cc,  sa*cc + ca*sb*sc,  ca*cb]
// ---------------------------------------------------------------------------
__global__ void setup_R_kernel(const float* __restrict__ eulers,
                               const float* __restrict__ trans,
                               float* __restrict__ Rt, int V) {
    int v = blockIdx.x * blockDim.x + threadIdx.x;
    if (v >= V) return;
    float a = eulers[3 * v + 0], b = eulers[3 * v + 1], c = eulers[3 * v + 2];
    float sa, ca, sb, cb, sc, cc;
    sincosf(a, &sa, &ca);
    sincosf(b, &sb, &cb);
    sincosf(c, &sc, &cc);
    float* o = Rt + 12 * v;
    o[0] = cb * cc;                 o[1] = -cb * sc;                o[2] = sb;
    o[3] = ca * sc + sa * sb * cc;  o[4] = ca * cc - sa * sb * sc;  o[5] = -sa * cb;
    o[6] = sa * sc - ca * sb * cc;  o[7] = sa * cc + ca * sb * sc;  o[8] = ca * cb;
    o[9] = trans[3 * v + 0];        o[10] = trans[3 * v + 1];       o[11] = trans[3 * v + 2];
}

// ---------------------------------------------------------------------------
// Main kernel: 4 points per thread.
//   loads : 3 x f32x4 (48 B, 16B-aligned) of packed xyz
//   stores: 2 x f32x4 (uv) + 1 x f32x4 (z), nontemporal streaming
// rcp + 1 Newton step instead of IEEE divide (threshold has huge headroom).
// ---------------------------------------------------------------------------
__global__ void __launch_bounds__(256)
proj4_kernel(const f32x4* __restrict__ pts4,
             const float* __restrict__ Rt,
             const float* __restrict__ focal_p,
             float* __restrict__ out,
             int N, int N4, long long VN) {
    const int t = blockIdx.x * blockDim.x + threadIdx.x;
    if (t >= N4) return;
    const int v = blockIdx.y;

    const float* __restrict__ p = Rt + 12 * v;
    const float p0 = p[0], p1 = p[1], p2 = p[2];
    const float p3 = p[3], p4 = p[4], p5 = p[5];
    const float p6 = p[6], p7 = p[7], p8 = p[8];
    const float tx = p[9], ty = p[10], tz = p[11];
    const float f  = *focal_p;
    const float nf = -f;

    const f32x4 q0 = pts4[3 * t + 0];
    const f32x4 q1 = pts4[3 * t + 1];
    const f32x4 q2 = pts4[3 * t + 2];

    const float Px[4] = {q0.x, q0.w, q1.z, q2.y};
    const float Py[4] = {q0.y, q1.x, q1.w, q2.z};
    const float Pz[4] = {q0.z, q1.y, q2.x, q2.w};

    float U[4], Vv[4], Zz[4];
#pragma unroll
    for (int i = 0; i < 4; ++i) {
        const float X = fmaf(p0, Px[i], fmaf(p1, Py[i], fmaf(p2, Pz[i], tx)));
        const float Y = fmaf(p3, Px[i], fmaf(p4, Py[i], fmaf(p5, Pz[i], ty)));
        const float Z = fmaf(p6, Px[i], fmaf(p7, Py[i], fmaf(p8, Pz[i], tz)));
        float r = __builtin_amdgcn_rcpf(Z);
        r = r * fmaf(-Z, r, 2.0f);            // one Newton step: ~1 ulp
        U[i]  = fmaf(nf * X, r, PCX);
        Vv[i] = fmaf(f  * Y, r, PCY);
        Zz[i] = Z;
    }

    f32x4* __restrict__ uvp = reinterpret_cast<f32x4*>(out)
                              + (long long)v * (N >> 1) + 2 * t;
    f32x4* __restrict__ zp  = reinterpret_cast<f32x4*>(out + 2 * VN)
                              + (long long)v * N4 + t;

    f32x4 uv0; uv0.x = U[0]; uv0.y = Vv[0]; uv0.z = U[1]; uv0.w = Vv[1];
    f32x4 uv1; uv1.x = U[2]; uv1.y = Vv[2]; uv1.z = U[3]; uv1.w = Vv[3];
    f32x4 zv;  zv.x = Zz[0]; zv.y = Zz[1]; zv.z = Zz[2]; zv.w = Zz[3];

    __builtin_nontemporal_store(uv0, uvp);
    __builtin_nontemporal_store(uv1, uvp + 1);
    __builtin_nontemporal_store(zv, zp);
}

// Scalar tail (only used if N % 4 != 0; N=250000 divides evenly).
__global__ void __launch_bounds__(64)
proj_tail_kernel(const float* __restrict__ pts,
                 const float* __restrict__ Rt,
                 const float* __restrict__ focal_p,
                 float* __restrict__ out,
                 int N, int n0, long long VN) {
    const int n = n0 + blockIdx.x * blockDim.x + threadIdx.x;
    if (n >= N) return;
    const int v = blockIdx.y;
    const float* p = Rt + 12 * v;
    const float f = *focal_p;
    const float x = pts[3 * n + 0], y = pts[3 * n + 1], z = pts[3 * n + 2];
    const float X = fmaf(p[0], x, fmaf(p[1], y, fmaf(p[2], z, p[9])));
    const float Y = fmaf(p[3], x, fmaf(p[4], y, fmaf(p[5], z, p[10])));
    const float Z = fmaf(p[6], x, fmaf(p[7], y, fmaf(p[8], z, p[11])));
    float r = __builtin_amdgcn_rcpf(Z);
    r = r * fmaf(-Z, r, 2.0f);
    const long long idx = (long long)v * N + n;
    out[2 * idx + 0] = fmaf(-f * X, r, PCX);
    out[2 * idx + 1] = fmaf( f * Y, r, PCY);
    out[2 * VN + idx] = Z;
}

extern "C" void kernel_launch(void* const* d_in, const int* in_sizes, int n_in,
                              void* d_out, int out_size, void* d_ws, size_t ws_size,
                              hipStream_t stream) {
    const float* focal  = (const float*)d_in[0];
    const float* eulers = (const float*)d_in[1];
    const float* trans  = (const float*)d_in[2];
    const float* pts    = (const float*)d_in[3];

    const int V = in_sizes[1] / 3;
    const int N = in_sizes[3] / 3;
    const int N4 = N / 4;
    const long long VN = (long long)V * N;

    float* out = (float*)d_out;
    float* Rt  = (float*)d_ws;   // 12*V floats; ws is plenty

    setup_R_kernel<<<dim3((V + 63) / 64), dim3(64), 0, stream>>>(eulers, trans, Rt, V);

    if (N4 > 0) {
        dim3 block(256, 1, 1);
        dim3 grid((N4 + 255) / 256, V, 1);
        proj4_kernel<<<grid, block, 0, stream>>>(
            reinterpret_cast<const f32x4*>(pts), Rt, focal, out, N, N4, VN);
    }
    const int rem = N - N4 * 4;
    if (rem > 0) {
        dim3 block(64, 1, 1);
        dim3 grid((rem + 63) / 64, V, 1);
        proj_tail_kernel<<<grid, block, 0, stream>>>(pts, Rt, focal, out, N, N4 * 4, VN);
    }
}

// Round 4
// 82.028 us; speedup vs baseline: 1.6059x; 1.6059x over previous
//
#include <hip/hip_runtime.h>

#define PCX 512.0f
#define PCY 512.0f
#define VCHUNK 16

typedef float f32x2 __attribute__((ext_vector_type(2)));
typedef float f32x4 __attribute__((ext_vector_type(4)));

// ---------------------------------------------------------------------------
// Setup: compose R = Rx(a)@Ry(b)@Rz(c), fold focal + sign + trans:
//   m[0..2] = -f*row0, c0 = -f*tx   ->  u = (m.P + c0)*(1/Z) + CX
//   m[3..5] =  f*row1, c1 =  f*ty   ->  v = (m.P + c1)*(1/Z) + CY
//   m[6..8] =    row2, c2 =     tz  ->  Z =  m.P + c2
// ---------------------------------------------------------------------------
__global__ void setup_R_kernel(const float* __restrict__ eulers,
                               const float* __restrict__ trans,
                               const float* __restrict__ focal_p,
                               float* __restrict__ Rt, int V) {
    int v = blockIdx.x * blockDim.x + threadIdx.x;
    if (v >= V) return;
    const float f = *focal_p;
    float a = eulers[3 * v + 0], b = eulers[3 * v + 1], c = eulers[3 * v + 2];
    float sa, ca, sb, cb, sc, cc;
    sincosf(a, &sa, &ca);
    sincosf(b, &sb, &cb);
    sincosf(c, &sc, &cc);
    const float r00 = cb * cc,                 r01 = -cb * sc,                r02 = sb;
    const float r10 = ca * sc + sa * sb * cc,  r11 = ca * cc - sa * sb * sc,  r12 = -sa * cb;
    const float r20 = sa * sc - ca * sb * cc,  r21 = sa * cc + ca * sb * sc,  r22 = ca * cb;
    float* o = Rt + 12 * v;
    o[0] = -f * r00;  o[1] = -f * r01;  o[2] = -f * r02;
    o[3] =  f * r10;  o[4] =  f * r11;  o[5] =  f * r12;
    o[6] =  r20;      o[7] =  r21;      o[8] =  r22;
    o[9]  = -f * trans[3 * v + 0];
    o[10] =  f * trans[3 * v + 1];
    o[11] =  trans[3 * v + 2];
}

// ---------------------------------------------------------------------------
// Main kernel: each thread owns 2 points (registers), loops over VCHUNK views.
// Reads points3d once per view-chunk (8x3MB total, not 128x).
// Per view-iter stores: float4 uv (coalesced 1KB/wave) + float2 z, both NT.
// ---------------------------------------------------------------------------
__global__ void __launch_bounds__(256)
proj_kernel(const f32x2* __restrict__ pts2,
            const float* __restrict__ Rt,
            float* __restrict__ out,
            int N, int Npairs, long long VN, int V, int nEven) {
    __shared__ float sp[VCHUNK * 12];
    const int v0 = blockIdx.y * VCHUNK;
    const int nv = min(VCHUNK, V - v0);
    for (int i = threadIdx.x; i < nv * 12; i += blockDim.x)
        sp[i] = Rt[v0 * 12 + i];
    __syncthreads();

    const int t = blockIdx.x * blockDim.x + threadIdx.x;
    if (t >= Npairs) return;

    const bool hasP1 = (2 * t + 1 < N);
    // load 2 points = 6 floats as 3x float2 (24B contiguous per thread)
    const f32x2 A = pts2[3 * t + 0];
    const f32x2 B = hasP1 ? pts2[3 * t + 1] : f32x2{0.f, 0.f};
    const f32x2 C = hasP1 ? pts2[3 * t + 2] : f32x2{pts2[3 * t + 1].x, 0.f};
    const float x0 = A.x, y0 = A.y;
    const float z0 = hasP1 ? B.x : C.x;
    const float x1 = B.y, y1 = C.x, z1 = C.y;

    const bool vec = nEven && hasP1;
    f32x4* __restrict__ uvp4 = reinterpret_cast<f32x4*>(out);
    f32x2* __restrict__ zp2  = reinterpret_cast<f32x2*>(out + 2 * VN);
    const int halfN = N >> 1;

    for (int v = v0; v < v0 + nv; ++v) {
        const float* __restrict__ p = sp + (v - v0) * 12;
        const float m0 = p[0], m1 = p[1], m2 = p[2];
        const float m3 = p[3], m4 = p[4], m5 = p[5];
        const float m6 = p[6], m7 = p[7], m8 = p[8];
        const float c0 = p[9], c1 = p[10], c2 = p[11];

        const float X0 = fmaf(m0, x0, fmaf(m1, y0, fmaf(m2, z0, c0)));
        const float Y0 = fmaf(m3, x0, fmaf(m4, y0, fmaf(m5, z0, c1)));
        const float Z0 = fmaf(m6, x0, fmaf(m7, y0, fmaf(m8, z0, c2)));
        const float r0 = __builtin_amdgcn_rcpf(Z0);
        const float u0 = fmaf(X0, r0, PCX);
        const float w0 = fmaf(Y0, r0, PCY);

        const float X1 = fmaf(m0, x1, fmaf(m1, y1, fmaf(m2, z1, c0)));
        const float Y1 = fmaf(m3, x1, fmaf(m4, y1, fmaf(m5, z1, c1)));
        const float Z1 = fmaf(m6, x1, fmaf(m7, y1, fmaf(m8, z1, c2)));
        const float r1 = __builtin_amdgcn_rcpf(Z1);
        const float u1 = fmaf(X1, r1, PCX);
        const float w1 = fmaf(Y1, r1, PCY);

        if (vec) {
            f32x4 uvv; uvv.x = u0; uvv.y = w0; uvv.z = u1; uvv.w = w1;
            f32x2 zz;  zz.x = Z0;  zz.y = Z1;
            __builtin_nontemporal_store(uvv, uvp4 + (long long)v * halfN + t);
            __builtin_nontemporal_store(zz,  zp2  + (long long)v * halfN + t);
        } else {
            const long long n = 2LL * t;
            const long long idx = (long long)v * N + n;
            out[2 * idx + 0] = u0;
            out[2 * idx + 1] = w0;
            out[2 * VN + idx] = Z0;
            if (hasP1) {
                out[2 * idx + 2] = u1;
                out[2 * idx + 3] = w1;
                out[2 * VN + idx + 1] = Z1;
            }
        }
    }
}

extern "C" void kernel_launch(void* const* d_in, const int* in_sizes, int n_in,
                              void* d_out, int out_size, void* d_ws, size_t ws_size,
                              hipStream_t stream) {
    const float* focal  = (const float*)d_in[0];
    const float* eulers = (const float*)d_in[1];
    const float* trans  = (const float*)d_in[2];
    const float* pts    = (const float*)d_in[3];

    const int V = in_sizes[1] / 3;
    const int N = in_sizes[3] / 3;
    const int Npairs = (N + 1) / 2;
    const long long VN = (long long)V * N;
    const int nEven = (N % 2 == 0) ? 1 : 0;

    float* out = (float*)d_out;
    float* Rt  = (float*)d_ws;   // 12*V floats

    setup_R_kernel<<<dim3((V + 63) / 64), dim3(64), 0, stream>>>(
        eulers, trans, focal, Rt, V);

    dim3 block(256, 1, 1);
    dim3 grid((Npairs + 255) / 256, (V + VCHUNK - 1) / VCHUNK, 1);
    proj_kernel<<<grid, block, 0, stream>>>(
        reinterpret_cast<const f32x2*>(pts), Rt, out, N, Npairs, VN, V, nEven);
}